// Round 1
// baseline (172.690 us; speedup 1.0000x reference)
//
#include <hip/hip_runtime.h>
#include <hip/hip_bf16.h>
#include <cstdint>

// SelfSimilarity: out[b,i,j] = softmax_j( -T * max(||x_i - x_j||^2, 0) )
// Strategy: bf16 MFMA for dots (norm expansion), max-logit is exactly 0 so
// softmax needs only a sum pass + a recompute/write pass.

using bf16x8 = __attribute__((ext_vector_type(8))) short;
using f32x4  = __attribute__((ext_vector_type(4))) float;

#define TEMP (1.0f / 13.544f)

#define GLOBAL_AS __attribute__((address_space(1)))
#define LDS_AS    __attribute__((address_space(3)))

// ---------------------------------------------------------------------------
// prep: fp32 -> bf16 (RNE) in MFMA-staging layout + csq[row] = -T*||x_bf||^2
// ws bf16 layout: [b][group=row>>4][qblock=k>>3][r=row&15][8 elems]
//   -> uint4 index: (b*128+g)*256 + q*16 + r
// ---------------------------------------------------------------------------
__global__ __launch_bounds__(256) void prep_kernel(
    const float* __restrict__ x, uint4* __restrict__ xbf, float* __restrict__ csq)
{
    const int t   = threadIdx.x;
    const int lr  = t >> 4;            // local row 0..15
    const int q   = t & 15;            // k-block of 8
    const int row = blockIdx.x * 16 + lr;   // 0..16383

    const float* xp = x + (size_t)row * 128 + q * 8;
    float4 a0 = *(const float4*)(xp);
    float4 a1 = *(const float4*)(xp + 4);
    float v[8] = {a0.x, a0.y, a0.z, a0.w, a1.x, a1.y, a1.z, a1.w};

    unsigned u[8];
    float s = 0.f;
#pragma unroll
    for (int e = 0; e < 8; ++e) {
        unsigned ui = __float_as_uint(v[e]);
        unsigned r  = (ui + 0x7FFFu + ((ui >> 16) & 1u)) >> 16;   // RNE to bf16
        u[e] = r;
        float d = __uint_as_float(r << 16);                        // decoded value
        s += d * d;                                                // norm of ROUNDED vec
    }
    uint4 pack;
    pack.x = u[0] | (u[1] << 16);
    pack.y = u[2] | (u[3] << 16);
    pack.z = u[4] | (u[5] << 16);
    pack.w = u[6] | (u[7] << 16);

    const int b  = row >> 11;
    const int g  = (row >> 4) & 127;
    const int rr = row & 15;
    xbf[(b * 128 + g) * 256 + q * 16 + rr] = pack;

#pragma unroll
    for (int m = 1; m < 16; m <<= 1) s += __shfl_xor(s, m, 64);
    if (q == 0) csq[row] = s * (-TEMP);
}

// ---------------------------------------------------------------------------
// main: per workgroup, M=32 rows x all 2048 cols. 4 waves split 128-col tiles
// (wave w -> cols w*32..w*32+31). A fragments pinned in registers.
// Pass 0: accumulate row sums of exp(logit). Pass 1: recompute, scale, store.
// logit = 2T*dot + csq_i + csq_j  (== -T*dist), clamped to <= 0.
// ---------------------------------------------------------------------------
__global__ __launch_bounds__(256, 2) void sim_kernel(
    const uint4* __restrict__ xbf, const float* __restrict__ csq, float* __restrict__ out)
{
    const int blk  = blockIdx.x;
    const int b    = blk >> 6;            // 64 row-tiles per batch
    const int i0   = (blk & 63) * 32;
    const int tid  = threadIdx.x;
    const int w    = tid >> 6;
    const int lane = tid & 63;
    const int quad = lane >> 4;
    const int l15  = lane & 15;

    __shared__ __align__(16) ushort lsB[16384];   // 32 KB: 128 cols x 128 k bf16
    __shared__ float lsSum[4][32];
    __shared__ float lsInv[32];

    const uint4* xbb  = xbf + (size_t)b * (128 * 256);
    const float* csqb = csq + b * 2048;

    // A fragments: rows i0..i0+31, all K. lane holds row (l15), k = quad*8.. per k4.
    bf16x8 afrag[2][4];
#pragma unroll
    for (int m = 0; m < 2; ++m)
#pragma unroll
        for (int k4 = 0; k4 < 4; ++k4) {
            uint4 vv = xbb[((i0 >> 4) + m) * 256 + (k4 * 4 + quad) * 16 + l15];
            afrag[m][k4] = __builtin_bit_cast(bf16x8, vv);
        }

    float csqi[2][4];
#pragma unroll
    for (int m = 0; m < 2; ++m) {
        float4 vv = *(const float4*)(csqb + i0 + m * 16 + quad * 4);
        csqi[m][0] = vv.x; csqi[m][1] = vv.y; csqi[m][2] = vv.z; csqi[m][3] = vv.w;
    }

    const float C2 = 2.0f * TEMP;
    const int   c0 = w * 32;
    float* outrow = out + ((size_t)b * 2048 + i0) * 2048;

    float sum_[2][4] = {};
    float inv_[2][4];

#pragma unroll 1
    for (int pass = 0; pass < 2; ++pass) {
#pragma unroll 1
        for (int jt = 0; jt < 16; ++jt) {
            const int j0 = jt * 128;
            __syncthreads();   // previous tile's ds_reads done before overwrite
            {
                // stage 32 KB B-tile: wave w copies 8 KB, 8 x (64 lanes x 16B)
                const uint4* src = xbb + (j0 >> 4) * 256 + w * 512 + lane;
#pragma unroll
                for (int it = 0; it < 8; ++it) {
                    __builtin_amdgcn_global_load_lds(
                        (const GLOBAL_AS void*)(src + it * 64),
                        (LDS_AS void*)(&lsB[w * 4096 + it * 512]),
                        16, 0, 0);
                }
            }
            __syncthreads();   // drains vmcnt before ds_reads

            const float csqj0 = csqb[j0 + c0 + l15];
            const float csqj1 = csqb[j0 + c0 + 16 + l15];

            f32x4 acc[2][2] = {};
#pragma unroll
            for (int k4 = 0; k4 < 4; ++k4) {
                const int qq = k4 * 4 + quad;
                bf16x8 b0 = *(const bf16x8*)(&lsB[(w * 2 + 0) * 2048 + qq * 128 + l15 * 8]);
                bf16x8 b1 = *(const bf16x8*)(&lsB[(w * 2 + 1) * 2048 + qq * 128 + l15 * 8]);
#pragma unroll
                for (int m = 0; m < 2; ++m) {
                    acc[m][0] = __builtin_amdgcn_mfma_f32_16x16x32_bf16(afrag[m][k4], b0, acc[m][0], 0, 0, 0);
                    acc[m][1] = __builtin_amdgcn_mfma_f32_16x16x32_bf16(afrag[m][k4], b1, acc[m][1], 0, 0, 0);
                }
            }

            if (pass == 0) {
#pragma unroll
                for (int m = 0; m < 2; ++m)
#pragma unroll
                    for (int n = 0; n < 2; ++n) {
                        const float cj = n ? csqj1 : csqj0;
#pragma unroll
                        for (int r = 0; r < 4; ++r) {
                            float lg = fminf(fmaf(C2, acc[m][n][r], csqi[m][r] + cj), 0.f);
                            sum_[m][r] += __expf(lg);
                        }
                    }
            } else {
#pragma unroll
                for (int m = 0; m < 2; ++m)
#pragma unroll
                    for (int r = 0; r < 4; ++r) {
                        float* op = outrow + (size_t)(m * 16 + quad * 4 + r) * 2048 + j0 + c0 + l15;
#pragma unroll
                        for (int n = 0; n < 2; ++n) {
                            const float cj = n ? csqj1 : csqj0;
                            float lg = fminf(fmaf(C2, acc[m][n][r], csqi[m][r] + cj), 0.f);
                            op[n * 16] = __expf(lg) * inv_[m][r];
                        }
                    }
            }
        }

        if (pass == 0) {
            // reduce sums across the 16 lanes of each row (bits 0..3 only)
#pragma unroll
            for (int m = 0; m < 2; ++m)
#pragma unroll
                for (int r = 0; r < 4; ++r) {
                    float s = sum_[m][r];
                    s += __shfl_xor(s, 1, 64);
                    s += __shfl_xor(s, 2, 64);
                    s += __shfl_xor(s, 4, 64);
                    s += __shfl_xor(s, 8, 64);
                    sum_[m][r] = s;
                }
            if (l15 == 0) {
#pragma unroll
                for (int m = 0; m < 2; ++m)
#pragma unroll
                    for (int r = 0; r < 4; ++r)
                        lsSum[w][m * 16 + quad * 4 + r] = sum_[m][r];
            }
            __syncthreads();
            if (tid < 32) {
                float tot = lsSum[0][tid] + lsSum[1][tid] + lsSum[2][tid] + lsSum[3][tid];
                lsInv[tid] = 1.0f / tot;
            }
            __syncthreads();
#pragma unroll
            for (int m = 0; m < 2; ++m) {
                float4 vv = *(const float4*)(&lsInv[m * 16 + quad * 4]);
                inv_[m][0] = vv.x; inv_[m][1] = vv.y; inv_[m][2] = vv.z; inv_[m][3] = vv.w;
            }
        }
    }
}

extern "C" void kernel_launch(void* const* d_in, const int* in_sizes, int n_in,
                              void* d_out, int out_size, void* d_ws, size_t ws_size,
                              hipStream_t stream) {
    const float* x   = (const float*)d_in[0];
    float*       out = (float*)d_out;
    // ws: [0, 4MB) packed bf16 x; [4MB, 4MB+64KB) csq. Needs ~4.26 MB of ws.
    uint4* xbf = (uint4*)d_ws;
    float* csq = (float*)((char*)d_ws + (size_t)4 * 1024 * 1024);

    prep_kernel<<<1024, 256, 0, stream>>>(x, xbf, csq);   // 16384 rows
    sim_kernel<<<512, 256, 0, stream>>>(xbf, csq, out);   // 8 batches x 64 row-tiles
}

// Round 2
// 170.194 us; speedup vs baseline: 1.0147x; 1.0147x over previous
//
#include <hip/hip_runtime.h>
#include <hip/hip_bf16.h>
#include <cstdint>

// SelfSimilarity: out[b,i,j] = softmax_j( -T * max(||x_i - x_j||^2, 0) )
// bf16 MFMA via norm expansion; ||x||^2 computed from ROUNDED bf16 values so
// the diagonal logit is exactly 0 => max logit is 0 => no online max needed.
// Single sweep: P kept in registers (M=16 rows/block), sums reduced, then a
// pure store burst. log2(e) folded into the scaling so epilogue is exp2.

using bf16x8 = __attribute__((ext_vector_type(8))) short;
using f32x4  = __attribute__((ext_vector_type(4))) float;

#define TEMP   (1.0f / 13.544f)
#define LOG2E  1.4426950408889634f

#define GLOBAL_AS __attribute__((address_space(1)))
#define LDS_AS    __attribute__((address_space(3)))

// ---------------------------------------------------------------------------
// prep: fp32 -> bf16 (RNE) in MFMA-staging layout + csq[row] = -T*log2e*||x_bf||^2
// ws bf16 layout: [b][group=row>>4][qblock=k>>3][r=row&15][8 elems]
//   -> uint4 index: (b*128+g)*256 + q*16 + r
// ---------------------------------------------------------------------------
__global__ __launch_bounds__(256) void prep_kernel(
    const float* __restrict__ x, uint4* __restrict__ xbf, float* __restrict__ csq)
{
    const int t   = threadIdx.x;
    const int lr  = t >> 4;            // local row 0..15
    const int q   = t & 15;            // k-block of 8
    const int row = blockIdx.x * 16 + lr;   // 0..16383

    const float* xp = x + (size_t)row * 128 + q * 8;
    float4 a0 = *(const float4*)(xp);
    float4 a1 = *(const float4*)(xp + 4);
    float v[8] = {a0.x, a0.y, a0.z, a0.w, a1.x, a1.y, a1.z, a1.w};

    unsigned u[8];
    float s = 0.f;
#pragma unroll
    for (int e = 0; e < 8; ++e) {
        unsigned ui = __float_as_uint(v[e]);
        unsigned r  = (ui + 0x7FFFu + ((ui >> 16) & 1u)) >> 16;   // RNE to bf16
        u[e] = r;
        float d = __uint_as_float(r << 16);                        // decoded value
        s += d * d;                                                // norm of ROUNDED vec
    }
    uint4 pack;
    pack.x = u[0] | (u[1] << 16);
    pack.y = u[2] | (u[3] << 16);
    pack.z = u[4] | (u[5] << 16);
    pack.w = u[6] | (u[7] << 16);

    const int b  = row >> 11;
    const int g  = (row >> 4) & 127;
    const int rr = row & 15;
    xbf[(b * 128 + g) * 256 + q * 16 + rr] = pack;

#pragma unroll
    for (int m = 1; m < 16; m <<= 1) s += __shfl_xor(s, m, 64);
    if (q == 0) csq[row] = s * (-TEMP * LOG2E);
}

// ---------------------------------------------------------------------------
// main: per workgroup, M=16 rows x all 2048 cols, single sweep.
// 4 waves split each 128-col j-tile (wave w -> cols w*32..w*32+31).
// A fragments pinned in registers; P (exp values) pinned in registers
// (16 tiles x 2 x 4 = 128 fp32/lane); row sums accumulated inline; then
// cross-lane/wave reduce; then pure store burst of P * inv.
// logit2 = log2e*(-T*dist) = C2L*dot + csq_i + csq_j, clamped <= 0.
// ---------------------------------------------------------------------------
__global__ __launch_bounds__(256, 2) void sim_kernel(
    const uint4* __restrict__ xbf, const float* __restrict__ csq, float* __restrict__ out)
{
    const int blk  = blockIdx.x;
    const int b    = blk >> 7;            // 128 row-tiles per batch
    const int i0   = (blk & 127) * 16;
    const int tid  = threadIdx.x;
    const int w    = tid >> 6;
    const int lane = tid & 63;
    const int quad = lane >> 4;
    const int l15  = lane & 15;

    __shared__ __align__(16) ushort lsB[16384];   // 32 KB: 128 cols x 128 k bf16
    __shared__ float lsSum[4][16];
    __shared__ __align__(16) float lsInv[16];

    const uint4* xbb  = xbf + (size_t)b * (128 * 256);
    const float* csqb = csq + b * 2048;

    // A fragments: rows i0..i0+15, all K. lane holds row l15, k-block quad per k4.
    bf16x8 afrag[4];
#pragma unroll
    for (int k4 = 0; k4 < 4; ++k4) {
        uint4 vv = xbb[(i0 >> 4) * 256 + (k4 * 4 + quad) * 16 + l15];
        afrag[k4] = __builtin_bit_cast(bf16x8, vv);
    }

    float csqi[4];
    {
        float4 vv = *(const float4*)(csqb + i0 + quad * 4);
        csqi[0] = vv.x; csqi[1] = vv.y; csqi[2] = vv.z; csqi[3] = vv.w;
    }

    const float C2L = 2.0f * TEMP * LOG2E;
    const int   c0  = w * 32;

    float P[16][2][4];
    float sum_[4] = {};

#pragma unroll
    for (int jt = 0; jt < 16; ++jt) {
        const int j0 = jt * 128;
        __syncthreads();   // previous tile's ds_reads done before overwrite
        {
            // stage 32 KB B-tile: wave w copies 8 KB, 8 x (64 lanes x 16B)
            const uint4* src = xbb + (j0 >> 4) * 256 + w * 512 + lane;
#pragma unroll
            for (int it = 0; it < 8; ++it) {
                __builtin_amdgcn_global_load_lds(
                    (const GLOBAL_AS void*)(src + it * 64),
                    (LDS_AS void*)(&lsB[w * 4096 + it * 512]),
                    16, 0, 0);
            }
        }
        __syncthreads();   // drains vmcnt before ds_reads

        const float csqj0 = csqb[j0 + c0 + l15];
        const float csqj1 = csqb[j0 + c0 + 16 + l15];

        f32x4 acc[2] = {};
#pragma unroll
        for (int k4 = 0; k4 < 4; ++k4) {
            const int qq = k4 * 4 + quad;
            bf16x8 b0 = *(const bf16x8*)(&lsB[(w * 2 + 0) * 2048 + qq * 128 + l15 * 8]);
            bf16x8 b1 = *(const bf16x8*)(&lsB[(w * 2 + 1) * 2048 + qq * 128 + l15 * 8]);
            acc[0] = __builtin_amdgcn_mfma_f32_16x16x32_bf16(afrag[k4], b0, acc[0], 0, 0, 0);
            acc[1] = __builtin_amdgcn_mfma_f32_16x16x32_bf16(afrag[k4], b1, acc[1], 0, 0, 0);
        }

#pragma unroll
        for (int n = 0; n < 2; ++n) {
            const float cj = n ? csqj1 : csqj0;
#pragma unroll
            for (int r = 0; r < 4; ++r) {
                float lg = fminf(fmaf(C2L, acc[n][r], csqi[r] + cj), 0.f);
                float p  = exp2f(lg);
                P[jt][n][r] = p;
                sum_[r] += p;
            }
        }
    }

    // reduce sums: over the 16-lane col groups (bits 0..3), then across waves
#pragma unroll
    for (int r = 0; r < 4; ++r) {
        float s = sum_[r];
        s += __shfl_xor(s, 1, 64);
        s += __shfl_xor(s, 2, 64);
        s += __shfl_xor(s, 4, 64);
        s += __shfl_xor(s, 8, 64);
        sum_[r] = s;
    }
    if (l15 == 0) {
#pragma unroll
        for (int r = 0; r < 4; ++r) lsSum[w][quad * 4 + r] = sum_[r];
    }
    __syncthreads();
    if (tid < 16) {
        float tot = lsSum[0][tid] + lsSum[1][tid] + lsSum[2][tid] + lsSum[3][tid];
        lsInv[tid] = 1.0f / tot;
    }
    __syncthreads();

    float inv_[4];
    {
        float4 vv = *(const float4*)(&lsInv[quad * 4]);
        inv_[0] = vv.x; inv_[1] = vv.y; inv_[2] = vv.z; inv_[3] = vv.w;
    }

    // store burst: 128 scalar dword stores per lane; each wave-inst covers
    // 4 rows x 64B contiguous segments — fully coalescable.
    float* outrow = out + ((size_t)b * 2048 + i0) * 2048;
#pragma unroll
    for (int jt = 0; jt < 16; ++jt) {
#pragma unroll
        for (int r = 0; r < 4; ++r) {
            float* op = outrow + (size_t)(quad * 4 + r) * 2048 + jt * 128 + c0 + l15;
            op[0]  = P[jt][0][r] * inv_[r];
            op[16] = P[jt][1][r] * inv_[r];
        }
    }
}

extern "C" void kernel_launch(void* const* d_in, const int* in_sizes, int n_in,
                              void* d_out, int out_size, void* d_ws, size_t ws_size,
                              hipStream_t stream) {
    const float* x   = (const float*)d_in[0];
    float*       out = (float*)d_out;
    // ws: [0, 4MB) packed bf16 x; [4MB, 4MB+64KB) csq. Needs ~4.26 MB of ws.
    uint4* xbf = (uint4*)d_ws;
    float* csq = (float*)((char*)d_ws + (size_t)4 * 1024 * 1024);

    prep_kernel<<<1024, 256, 0, stream>>>(x, xbf, csq);     // 16384 rows
    sim_kernel<<<1024, 256, 0, stream>>>(xbf, csq, out);    // 8 batches x 128 row-tiles
}